// Round 1
// 493.358 us; speedup vs baseline: 1.5122x; 1.5122x over previous
//
#include <hip/hip_runtime.h>

#define Bn   32
#define QL   32
#define DOCn 2048
#define Sn   64
#define En   300
#define Hn   256

typedef short bf16x8 __attribute__((ext_vector_type(8)));
typedef short s16x4  __attribute__((ext_vector_type(4)));
typedef float f32x4  __attribute__((ext_vector_type(4)));

static __device__ __forceinline__ float b2f(short s){
  unsigned int u = ((unsigned int)(unsigned short)s) << 16;
  float f; __builtin_memcpy(&f, &u, 4); return f;
}
static __device__ __forceinline__ short f2b(float f){
  unsigned int u; __builtin_memcpy(&u, &f, 4);
  u = u + 0x7fffu + ((u >> 16) & 1u);
  return (short)(u >> 16);
}
static __device__ __forceinline__ float sigm(float x){ return 1.0f/(1.0f+__expf(-x)); }
static __device__ __forceinline__ float tanhx(float x){ return 1.0f - 2.0f/(__expf(2.0f*x)+1.0f); }
static __device__ __forceinline__ f32x4 mfma16(bf16x8 a, bf16x8 b, f32x4 c){
  return __builtin_amdgcn_mfma_f32_16x16x32_bf16(a, b, c, 0, 0, 0);
}
// barrier that drains LDS only (no vmcnt(0) store/load drain like __syncthreads)
static __device__ __forceinline__ void bar_lgkm(){
  asm volatile("s_waitcnt lgkmcnt(0)\n\ts_barrier" ::: "memory");
}

// ---------------------------------------------------------------- facts ----
__global__ __launch_bounds__(256) void k_facts(
    const int* __restrict__ docs, const int* __restrict__ slens,
    const float* __restrict__ emb, short* __restrict__ facts)
{
  __shared__ int pref[2*Sn];
  const int blk = blockIdx.x;
  const int b = blk >> 6, s = blk & 63;
  const int tid = threadIdx.x;
  if (tid < Sn){                       // wave 0: parallel prefix over lens
    const int v = slens[b*Sn + tid];
    int x = v;
#pragma unroll
    for (int d = 1; d < 64; d <<= 1){
      const int y = __shfl_up(x, d, 64);
      if (tid >= d) x += y;
    }
    pref[tid] = x - v;                 // exclusive prefix
    pref[Sn + tid] = v;
  }
  __syncthreads();
  const int off = pref[s];
  const int len = pref[Sn + s];
  const int e0 = tid;
  float a0 = 0.f, a1 = 0.f;
  const int* dtok = docs + b*DOCn + off;
  int tk = (len > 0) ? dtok[0] : 0;
  for (int l = 0; l < len; ++l){       // token-id lookahead hides gather latency
    const int tkn = (l + 1 < len) ? dtok[l+1] : 0;
    const float* row = emb + (long)tk*En;
    a0 += row[e0];
    if (e0 + 256 < En) a1 += row[e0+256];
    tk = tkn;
  }
  const float inv = 1.0f / (float)(len > 0 ? len : 1);
  short* frow = facts + ((long)b*Sn + s)*En;
  frow[e0] = f2b(a0*inv);
  if (e0 + 256 < En) frow[e0+256] = f2b(a1*inv);
}

// ------------------------------------------------------------- q_xg GEMM ---
__global__ __launch_bounds__(256) void k_xg_q(
    const int* __restrict__ queries, const float* __restrict__ emb,
    const float* __restrict__ wih, const float* __restrict__ bih,
    short* __restrict__ xg)
{
  __shared__ alignas(16) short Al[2][64][40];
  const int bm = blockIdx.x, bn = blockIdx.y;
  const int tid = threadIdx.x;
  const int l = tid & 63, w = tid >> 6;
  const int wm = w & 1, wn = w >> 1;
  const int l15 = l & 15, lq = l >> 4;

  bf16x8 bfr[2][10];
#pragma unroll
  for (int nt = 0; nt < 2; ++nt){
    const int g = bn*64 + wn*32 + nt*16 + l15;
    const float* wr = wih + (long)g*En;
#pragma unroll
    for (int kk = 0; kk < 10; ++kk){
      const int k0 = kk*32 + lq*8;
      bf16x8 v;
      if (k0 + 7 < En){
        const f32x4 f0 = *(const f32x4*)(wr + k0);
        const f32x4 f1 = *(const f32x4*)(wr + k0 + 4);
#pragma unroll
        for (int j = 0; j < 4; ++j){ v[j] = f2b(f0[j]); v[4+j] = f2b(f1[j]); }
      } else {
#pragma unroll
        for (int j = 0; j < 8; ++j){ const int k = k0 + j; v[j] = (k < En) ? f2b(wr[k]) : (short)0; }
      }
      bfr[nt][kk] = v;
    }
  }

  const int arow = l;
  const int ak8  = w*8;
  const int tok  = queries[bm*64 + arow];
  const float* asrc = emb + (long)tok*En;

  float ar[8];
#define LDA_Q(KK) do{ const int k0_ = (KK)*32 + ak8; \
    if (k0_ + 7 < En){ const f32x4 f0_ = *(const f32x4*)(asrc+k0_), f1_ = *(const f32x4*)(asrc+k0_+4); \
      ar[0]=f0_[0];ar[1]=f0_[1];ar[2]=f0_[2];ar[3]=f0_[3];ar[4]=f1_[0];ar[5]=f1_[1];ar[6]=f1_[2];ar[7]=f1_[3]; } \
    else { _Pragma("unroll") for (int j=0;j<8;++j){ const int k_=k0_+j; ar[j] = (k_<En)? asrc[k_] : 0.f; } } }while(0)
#define STA_Q(BUF) do{ s16x4 s0_ = (s16x4){f2b(ar[0]),f2b(ar[1]),f2b(ar[2]),f2b(ar[3])}; \
    s16x4 s1_ = (s16x4){f2b(ar[4]),f2b(ar[5]),f2b(ar[6]),f2b(ar[7])}; \
    *(s16x4*)&Al[BUF][arow][ak8] = s0_; *(s16x4*)&Al[BUF][arow][ak8+4] = s1_; }while(0)

  LDA_Q(0); STA_Q(0);
  __syncthreads();

  f32x4 acc[2][2] = {};
#pragma unroll
  for (int kk = 0; kk < 10; ++kk){
    if (kk < 9) LDA_Q(kk+1);
#pragma unroll
    for (int mt = 0; mt < 2; ++mt){
      bf16x8 a = *(const bf16x8*)&Al[kk&1][wm*32 + mt*16 + l15][lq*8];
      acc[mt][0] = mfma16(a, bfr[0][kk], acc[mt][0]);
      acc[mt][1] = mfma16(a, bfr[1][kk], acc[mt][1]);
    }
    if (kk < 9) STA_Q((kk+1)&1);
    __syncthreads();
  }
#undef LDA_Q
#undef STA_Q

#pragma unroll
  for (int nt = 0; nt < 2; ++nt){
    const int cc = bn*64 + wn*32 + nt*16 + l15;
    const float bias = bih[cc];
#pragma unroll
    for (int mt = 0; mt < 2; ++mt){
      const int r0 = bm*64 + wm*32 + mt*16 + lq*4;
#pragma unroll
      for (int p = 0; p < 4; ++p)
        xg[(long)(r0+p)*768 + cc] = f2b(acc[mt][nt][p] + bias);
    }
  }
}

// ------------------------------------------------------------ fact xg GEMM -
// A = facts (2048 x 300 bf16); z=0 -> f weights, z=1 -> b weights.
__global__ __launch_bounds__(256) void k_xg_fb(
    const short* __restrict__ facts,
    const float* __restrict__ f_wih, const float* __restrict__ f_bih,
    const float* __restrict__ b_wih, const float* __restrict__ b_bih,
    short* __restrict__ f_xg, short* __restrict__ b_xg)
{
  __shared__ alignas(16) short Al[2][64][40];
  const float* wih = blockIdx.z ? b_wih : f_wih;
  const float* bih = blockIdx.z ? b_bih : f_bih;
  short*       xg  = blockIdx.z ? b_xg  : f_xg;

  const int bm = blockIdx.x, bn = blockIdx.y;
  const int tid = threadIdx.x;
  const int l = tid & 63, w = tid >> 6;
  const int wm = w & 1, wn = w >> 1;
  const int l15 = l & 15, lq = l >> 4;

  bf16x8 bfr[2][10];
#pragma unroll
  for (int nt = 0; nt < 2; ++nt){
    const int g = bn*64 + wn*32 + nt*16 + l15;
    const float* wr = wih + (long)g*En;
#pragma unroll
    for (int kk = 0; kk < 10; ++kk){
      const int k0 = kk*32 + lq*8;
      bf16x8 v;
      if (k0 + 7 < En){
        const f32x4 f0 = *(const f32x4*)(wr + k0);
        const f32x4 f1 = *(const f32x4*)(wr + k0 + 4);
#pragma unroll
        for (int j = 0; j < 4; ++j){ v[j] = f2b(f0[j]); v[4+j] = f2b(f1[j]); }
      } else {
#pragma unroll
        for (int j = 0; j < 8; ++j){ const int k = k0 + j; v[j] = (k < En) ? f2b(wr[k]) : (short)0; }
      }
      bfr[nt][kk] = v;
    }
  }

  const int arow = l;
  const int ak8  = w*8;
  const short* asrc = facts + (long)(bm*64 + arow)*En;

  s16x4 a0_, a1_;
#define LDA_F(KK) do{ const int k0_ = (KK)*32 + ak8; \
    if (k0_ + 7 < En){ a0_ = *(const s16x4*)(asrc+k0_); a1_ = *(const s16x4*)(asrc+k0_+4); } \
    else { _Pragma("unroll") for (int j=0;j<4;++j){ const int ka_=k0_+j, kb_=k0_+4+j; \
      a0_[j] = (ka_<En)? asrc[ka_] : (short)0; a1_[j] = (kb_<En)? asrc[kb_] : (short)0; } } }while(0)
#define STA_F(BUF) do{ *(s16x4*)&Al[BUF][arow][ak8] = a0_; *(s16x4*)&Al[BUF][arow][ak8+4] = a1_; }while(0)

  LDA_F(0); STA_F(0);
  __syncthreads();

  f32x4 acc[2][2] = {};
#pragma unroll
  for (int kk = 0; kk < 10; ++kk){
    if (kk < 9) LDA_F(kk+1);
#pragma unroll
    for (int mt = 0; mt < 2; ++mt){
      bf16x8 a = *(const bf16x8*)&Al[kk&1][wm*32 + mt*16 + l15][lq*8];
      acc[mt][0] = mfma16(a, bfr[0][kk], acc[mt][0]);
      acc[mt][1] = mfma16(a, bfr[1][kk], acc[mt][1]);
    }
    if (kk < 9) STA_F((kk+1)&1);
    __syncthreads();
  }
#undef LDA_F
#undef STA_F

#pragma unroll
  for (int nt = 0; nt < 2; ++nt){
    const int cc = bn*64 + wn*32 + nt*16 + l15;
    const float bias = bih[cc];
#pragma unroll
    for (int mt = 0; mt < 2; ++mt){
      const int r0 = bm*64 + wm*32 + mt*16 + lq*4;
#pragma unroll
      for (int p = 0; p < 4; ++p)
        xg[(long)(r0+p)*768 + cc] = f2b(acc[mt][nt][p] + bias);
    }
  }
}

// ------------------------------------------------------------------ GRU ----
// 6 blocks x 1024 threads: (q,f,b) x 2 batch-halves of 16 rows.
// Register budget at 16 waves/CU is 128 unified regs/thread. Full wf[3][8]
// is 96 regs and (with acc + working set) spilled to scratch in the previous
// version (VGPR_Count=64 => 64+64 split + per-step scratch reloads). Fix:
// kk=0..5 fragments in regs (72), kk=6..7 fragments of all 3 gates in LDS
// per-thread slots (96KB). Plus: xg prefetch regs, double-buffered h tile,
// one lgkm-only barrier per step (no vmcnt(0) store drain).
__global__ __launch_bounds__(1024) void k_gru(
    const short* __restrict__ q_xg, const short* __restrict__ f_xg,
    const short* __restrict__ b_xg,
    const float* __restrict__ q_whh, const float* __restrict__ q_bhh,
    const float* __restrict__ f_whh, const float* __restrict__ f_bhh,
    const float* __restrict__ b_whh, const float* __restrict__ b_bhh,
    const int* __restrict__ qlens,
    short* __restrict__ f_hs, short* __restrict__ b_hs,
    float* __restrict__ dout)
{
  __shared__ alignas(16) short hl[2*4224];    // h double buffer, stride 264
  __shared__ alignas(16) short wl[6*1024*8];  // 96KB: kk=6,7 weight frags, slot per thread

  const int gru = blockIdx.x >> 1;   // 0=q, 1=f, 2=b
  const int mh  = blockIdx.x & 1;
  const int tid = threadIdx.x;
  const int l = tid & 63, w = tid >> 6;   // 16 waves
  const int l15 = l & 15, lq = l >> 4;

  const float* whh = (gru == 0) ? q_whh : (gru == 1) ? f_whh : b_whh;
  const float* bhh = (gru == 0) ? q_bhh : (gru == 1) ? f_bhh : b_bhh;
  const short* xg  = (gru == 0) ? q_xg  : (gru == 1) ? f_xg  : b_xg;
  const int T = (gru == 0) ? QL : Sn;

  const int c = w*16 + l15;          // this wave's gate column slice

  bf16x8 wf[3][6];                   // 72 VGPRs
  float bias[3];
#pragma unroll
  for (int gi = 0; gi < 3; ++gi){
    const int g = gi*256 + c;
    const float* wr = whh + (long)g*Hn;
#pragma unroll
    for (int kk = 0; kk < 8; ++kk){
      const f32x4 f0 = *(const f32x4*)(wr + kk*32 + lq*8);
      const f32x4 f1 = *(const f32x4*)(wr + kk*32 + lq*8 + 4);
      bf16x8 v;
#pragma unroll
      for (int j = 0; j < 4; ++j){ v[j] = f2b(f0[j]); v[4+j] = f2b(f1[j]); }
      if (kk < 6) wf[gi][kk] = v;
      else *(bf16x8*)&wl[((gi*2 + (kk-6))*1024 + tid)*8] = v;
    }
    bias[gi] = bhh[g];
  }

  for (int i = tid; i < 4224; i += 1024) hl[i] = 0;

  float hreg[4] = {};
  int qlen_m[4];
#pragma unroll
  for (int p = 0; p < 4; ++p) qlen_m[p] = qlens[mh*16 + lq*4 + p];

  const int rowT768 = T*768;
  const short* xbase = xg + (long)(mh*16 + lq*4)*rowT768 + c;
  short* hsb = ((gru == 1) ? f_hs : b_hs) + (long)(mh*16 + lq*4)*(Sn*Hn) + c;
  float* qdst = dout + (mh*16 + lq*4)*Hn + c;

  __syncthreads();   // wl + hl init visible

  short pre[12];     // xg prefetch for the current step (12 regs)
#define TOF(TT) ((gru == 2) ? (T - 1 - (TT)) : (TT))
#define LOADP(TI) do{ const int _to = (TI)*768; \
  _Pragma("unroll") for (int p = 0; p < 4; ++p){ \
    const short* _xr = xbase + p*rowT768 + _to; \
    pre[p*3+0] = _xr[0]; pre[p*3+1] = _xr[256]; pre[p*3+2] = _xr[512]; } }while(0)

#define GRU_STEP(TT, DOM, HIN, HOUT) do{ \
    f32x4 acc[3]; \
    _Pragma("unroll") for (int gi = 0; gi < 3; ++gi){ const float bv = bias[gi]; acc[gi] = (f32x4){bv,bv,bv,bv}; } \
    if (DOM){ \
      _Pragma("unroll") for (int kk = 0; kk < 6; ++kk){ \
        const bf16x8 a = *(const bf16x8*)&(HIN)[l15*264 + kk*32 + lq*8]; \
        acc[0] = mfma16(a, wf[0][kk], acc[0]); \
        acc[1] = mfma16(a, wf[1][kk], acc[1]); \
        acc[2] = mfma16(a, wf[2][kk], acc[2]); \
      } \
      _Pragma("unroll") for (int kk = 6; kk < 8; ++kk){ \
        const bf16x8 a  = *(const bf16x8*)&(HIN)[l15*264 + kk*32 + lq*8]; \
        const bf16x8 w0 = *(const bf16x8*)&wl[((0*2 + (kk-6))*1024 + tid)*8]; \
        const bf16x8 w1 = *(const bf16x8*)&wl[((1*2 + (kk-6))*1024 + tid)*8]; \
        const bf16x8 w2 = *(const bf16x8*)&wl[((2*2 + (kk-6))*1024 + tid)*8]; \
        acc[0] = mfma16(a, w0, acc[0]); \
        acc[1] = mfma16(a, w1, acc[1]); \
        acc[2] = mfma16(a, w2, acc[2]); \
      } \
    } \
    const int t_ = TOF(TT); \
    _Pragma("unroll") for (int p = 0; p < 4; ++p){ \
      const int r_ = lq*4 + p; \
      const float ir = b2f(pre[p*3+0]), iz = b2f(pre[p*3+1]), in_ = b2f(pre[p*3+2]); \
      const float rr = sigm(ir + acc[0][p]); \
      const float zz = sigm(iz + acc[1][p]); \
      const float nn = tanhx(in_ + rr*acc[2][p]); \
      const float hn = (1.0f - zz)*nn + zz*hreg[p]; \
      hreg[p] = hn; \
      (HOUT)[r_*264 + c] = f2b(hn); \
      if (gru == 0){ if (t_ == qlen_m[p] - 1) qdst[p*Hn] = hn; } \
      else { hsb[p*(Sn*Hn) + t_*Hn] = f2b(hn); } \
    } \
  }while(0)

  short* h0 = hl;
  short* h1 = hl + 4224;

  // peeled steps 0,1 (step 0: h=0 => acc=bias exactly, skip MFMA)
  LOADP(TOF(0));
  GRU_STEP(0, 0, h0, h1);
  LOADP(TOF(1));
  bar_lgkm();
  GRU_STEP(1, 1, h1, h0);
  LOADP(TOF(2));
  bar_lgkm();

  for (int tt = 2; tt < T; tt += 2){
    GRU_STEP(tt, 1, h0, h1);
    LOADP(TOF(tt+1));
    bar_lgkm();
    GRU_STEP(tt+1, 1, h1, h0);
    if (tt + 2 < T) LOADP(TOF(tt+2));
    bar_lgkm();
  }
#undef TOF
#undef LOADP
#undef GRU_STEP
}

// -------------------------------------------------------------- combine ----
__global__ __launch_bounds__(256) void k_combine(
    const short* __restrict__ f_hs, const short* __restrict__ b_hs,
    const int* __restrict__ slens, float* __restrict__ dout)
{
  const int i4 = (blockIdx.x*256 + threadIdx.x) * 4;   // 512 blocks cover 524288
  const s16x4 fv = *(const s16x4*)(f_hs + i4);
  const s16x4 bv = *(const s16x4*)(b_hs + i4);
  f32x4 o;
#pragma unroll
  for (int j = 0; j < 4; ++j) o[j] = b2f(fv[j]) + b2f(bv[j]);
  *(f32x4*)(dout + Bn*Hn + i4) = o;
  if (blockIdx.x == 0 && threadIdx.x < Bn){
    const int* ls = slens + threadIdx.x*Sn;
    int cnt = 0;
#pragma unroll
    for (int s = 0; s < Sn; ++s) cnt += (ls[s] > 0) ? 1 : 0;
    dout[Bn*Hn + Bn*Sn*Hn + threadIdx.x] = (float)cnt;
  }
}

// -------------------------------------------------------------- launch -----
extern "C" void kernel_launch(void* const* d_in, const int* in_sizes, int n_in,
                              void* d_out, int out_size, void* d_ws, size_t ws_size,
                              hipStream_t stream)
{
  const int*   queries = (const int*)d_in[0];
  const int*   qlens   = (const int*)d_in[1];
  const int*   docs    = (const int*)d_in[2];
  const int*   slens   = (const int*)d_in[3];
  const float* emb     = (const float*)d_in[4];
  const float* q_wih   = (const float*)d_in[5];
  const float* q_whh   = (const float*)d_in[6];
  const float* q_bih   = (const float*)d_in[7];
  const float* q_bhh   = (const float*)d_in[8];
  const float* f_wih   = (const float*)d_in[9];
  const float* f_whh   = (const float*)d_in[10];
  const float* f_bih   = (const float*)d_in[11];
  const float* f_bhh   = (const float*)d_in[12];
  const float* b_wih   = (const float*)d_in[13];
  const float* b_whh   = (const float*)d_in[14];
  const float* b_bih   = (const float*)d_in[15];
  const float* b_bhh   = (const float*)d_in[16];

  // Workspace (11.2 MB), layout unchanged:
  char* wsb = (char*)d_ws;
  short* f_xg  = (short*)(wsb);               // 2048*768 bf16 = 3,145,728 B
  short* b_xg  = (short*)(wsb +  3145728);    // 3,145,728 B
  short* q_xg  = (short*)(wsb +  6291456);    // 1024*768 bf16 = 1,572,864 B
  short* facts = (short*)(wsb +  7864320);    // 2048*300 bf16 = 1,228,800 B
  short* f_hs  = (short*)(wsb +  9093120);    // 32*64*256 bf16 = 1,048,576 B
  short* b_hs  = (short*)(wsb + 10141696);    // 1,048,576 B (end 11,190,272)

  float* dout = (float*)d_out;

  k_facts<<<dim3(Bn*Sn), 256, 0, stream>>>(docs, slens, emb, facts);
  k_xg_q <<<dim3(16, 12), 256, 0, stream>>>(queries, emb, q_wih, q_bih, q_xg);
  k_xg_fb<<<dim3(32, 12, 2), 256, 0, stream>>>(facts, f_wih, f_bih, b_wih, b_bih, f_xg, b_xg);
  k_gru  <<<dim3(6), 1024, 0, stream>>>(q_xg, f_xg, b_xg, q_whh, q_bhh,
                                        f_whh, f_bhh, b_whh, b_bhh,
                                        qlens, f_hs, b_hs, dout);
  k_combine<<<dim3(512), 256, 0, stream>>>(f_hs, b_hs, slens, dout);
}